// Round 10
// baseline (182.850 us; speedup 1.0000x reference)
//
#include <hip/hip_runtime.h>
#include <hip/hip_fp16.h>

#define N_NODES 100000
#define D 64
#define BR 256                     // nodes per bucket
#define NB 391                     // ceil(N_NODES / BR)
#define ECH 2560                   // edges per hist/partition block
#define NROWPAD 100096             // row capacity for feature buffers (>=N_NODES+1)
#define CSRCAP 6144                // LDS edge-staging capacity per bucket (+30 sigma)

typedef _Float16 f16x8 __attribute__((ext_vector_type(8)));
typedef float f32x4 __attribute__((ext_vector_type(4)));

__device__ __forceinline__ float rlf(float v, int l) {
    union { float f; int i; } u;
    u.f = v;
    u.i = __builtin_amdgcn_readlane(u.i, l);
    return u.f;
}

// ---------------- weight prep + x->fp16 + dummy-row zero + histT tail zero ------------
// frag f=(kt*NT+nt): elem (lane,i) = W_cat[kt*32+(lane>>4)*8+i][nt*16+(lane&15)]
__global__ __launch_bounds__(256) void k_prep(const float* __restrict__ Wl1, const float* __restrict__ Wr1,
                                              const float* __restrict__ Wl2, const float* __restrict__ Wr2,
                                              const float* __restrict__ Wl3, const float* __restrict__ Wr3,
                                              const float* __restrict__ Wfc,
                                              __half* __restrict__ Wf1, __half* __restrict__ Wf2,
                                              __half* __restrict__ Wf3, __half* __restrict__ Wffc,
                                              unsigned* __restrict__ x16, unsigned* __restrict__ H1,
                                              unsigned* __restrict__ H2,
                                              int* __restrict__ histT, int entries, int ntail,
                                              const float4* __restrict__ x, int n4) {
    int t = blockIdx.x * 256 + threadIdx.x;
    if (t >= 65536) {                      // x -> fp16 (bulk of the grid)
        int i = t - 65536;
        if (i < n4) {
            float4 v = x[i];
            union { __half2 h[2]; uint2 u; } pk;
            pk.h[0] = __floats2half2_rn(v.x, v.y);
            pk.h[1] = __floats2half2_rn(v.z, v.w);
            ((uint2*)x16)[i] = pk.u;
        }
    } else if (t < 24576) {                // 3 layers x 16 frags x 512
        int layer = t / 8192;
        int r = t % 8192;
        int f = r >> 9, rem = r & 511;
        int lane = rem >> 3, i = rem & 7;
        int kt = f >> 2, nt = f & 3;
        int k = kt * 32 + (lane >> 4) * 8 + i;   // 0..127 over [Wl|Wr]
        int o = nt * 16 + (lane & 15);
        const float* Wl = layer == 0 ? Wl1 : layer == 1 ? Wl2 : Wl3;
        const float* Wr = layer == 0 ? Wr1 : layer == 1 ? Wr2 : Wr3;
        float v = (k < 64) ? Wl[o * 64 + k] : Wr[o * 64 + (k - 64)];
        __half* Wf = layer == 0 ? Wf1 : layer == 1 ? Wf2 : Wf3;
        Wf[r] = __float2half(v);
    } else if (t < 26624) {                // fc: 4 frags x 512
        int r = t - 24576;
        int f = r >> 9, rem = r & 511;
        int lane = rem >> 3, i = rem & 7;
        int kt = f >> 1, nt = f & 1;
        int k = kt * 32 + (lane >> 4) * 8 + i;
        int o = nt * 16 + (lane & 15);
        Wffc[r] = __float2half(Wfc[o * 64 + k]);
    } else if (t < 26720) {                // zero dummy row N_NODES (32 uints each)
        int z = t - 26624;                 // 0..95
        unsigned* buf = (z >> 5) == 0 ? x16 : (z >> 5) == 1 ? H1 : H2;
        buf[(size_t)N_NODES * 32 + (z & 31)] = 0u;
    } else if (t >= 32768 && t < 32768 + ntail) {
        histT[entries + (t - 32768)] = 0;  // zero only the scan-padding tail
    }
}

// ---------------- CSR build (no global atomics) ----------------

__global__ __launch_bounds__(512) void k_hist(const int* __restrict__ dst,
                                              int* __restrict__ histT,
                                              int E, int ga) {
    __shared__ int h[NB];
    int blk = blockIdx.x, tid = threadIdx.x;
    for (int i = tid; i < NB; i += 512) h[i] = 0;
    __syncthreads();
    int base = blk * ECH;
    int lim = E - base; if (lim > ECH) lim = ECH;
    for (int i = tid; i < lim; i += 512)
        atomicAdd(&h[dst[base + i] >> 8], 1);
    __syncthreads();
    for (int i = tid; i < NB; i += 512)
        histT[i * ga + blk] = h[i];
}

__global__ __launch_bounds__(256) void k_scan1(const int* __restrict__ cnt,
                                               int* __restrict__ part,
                                               int* __restrict__ bsums) {
    __shared__ int s[256];
    int tid = threadIdx.x;
    int i4 = blockIdx.x * 256 + tid;
    int4 v = reinterpret_cast<const int4*>(cnt)[i4];
    int tsum = v.x + v.y + v.z + v.w;
    s[tid] = tsum;
    __syncthreads();
    for (int off = 1; off < 256; off <<= 1) {
        int t = 0;
        if (tid >= off) t = s[tid - off];
        __syncthreads();
        if (tid >= off) s[tid] += t;
        __syncthreads();
    }
    int excl = tid ? s[tid - 1] : 0;
    if (tid == 255) bsums[blockIdx.x] = s[255];
    int4 o;
    o.x = excl;
    o.y = o.x + v.x;
    o.z = o.y + v.y;
    o.w = o.z + v.z;
    reinterpret_cast<int4*>(part)[i4] = o;
}

// scan of block sums; also initializes the reserved col pad slots [0..7] = N_NODES
__global__ __launch_bounds__(256) void k_scan2(int* __restrict__ bsums, int nb,
                                               int* __restrict__ col) {
    __shared__ int s[256];
    int tid = threadIdx.x;
    if (tid < 8) col[tid] = N_NODES;
    int v = (tid < nb) ? bsums[tid] : 0;
    s[tid] = v;
    __syncthreads();
    for (int off = 1; off < 256; off <<= 1) {
        int t = 0;
        if (tid >= off) t = s[tid - off];
        __syncthreads();
        if (tid >= off) s[tid] += t;
        __syncthreads();
    }
    if (tid < nb) bsums[tid] = tid ? s[tid - 1] : 0;
}

// partition into bucket-major, packed edge = src | (ldst<<17); bsums folded in
__global__ __launch_bounds__(512) void k_part(const int* __restrict__ src,
                                              const int* __restrict__ dst,
                                              const int* __restrict__ offs,
                                              const int* __restrict__ bsums,
                                              int* __restrict__ bedge,
                                              int E, int ga) {
    __shared__ int o[NB];
    int blk = blockIdx.x, tid = threadIdx.x;
    for (int i = tid; i < NB; i += 512) {
        int ent = i * ga + blk;
        o[i] = offs[ent] + bsums[ent >> 10];
    }
    __syncthreads();
    int base = blk * ECH;
    int lim = E - base; if (lim > ECH) lim = ECH;
    for (int i = tid; i < lim; i += 512) {
        int e = base + i;
        int d = dst[e];
        int pos = atomicAdd(&o[d >> 8], 1);
        bedge[pos] = src[e] | ((d & 255) << 17);
    }
}

// per-bucket CSR, single global pass: edges staged in LDS during counting, scattered
// from LDS. Degree padded to x4; dummy index = N_NODES (zero row). col region for
// bucket b: [ebeg + b*1024 + 8, ...) — slots 0..7 reserved as pad target.
__global__ __launch_bounds__(512) void k_csr(const int* __restrict__ bedge,
                                             const int* __restrict__ offs,
                                             const int* __restrict__ bsums,
                                             int* __restrict__ col,
                                             int2* __restrict__ rp,
                                             float* __restrict__ deg_inv,
                                             int E, int ga) {
    __shared__ int ebuf[CSRCAP];
    __shared__ int lcnt[BR];
    __shared__ int stmp[BR];
    __shared__ int lcur[BR];
    int b = blockIdx.x, tid = threadIdx.x;
    int e0 = b * ga;
    int ebeg = offs[e0] + bsums[e0 >> 10];
    int eend = E;
    if (b + 1 < NB) {
        int e1 = (b + 1) * ga;
        eend = offs[e1] + bsums[e1 >> 10];
    }
    int cnt = eend - ebeg;
    int nbase = b * BR;
    int cbase = ebeg + b * (BR * 4) + 8;
    if (tid < 256) lcnt[tid] = 0;
    __syncthreads();
    for (int i = tid; i < cnt; i += 512) {          // single global read pass
        int ed = bedge[ebeg + i];
        if (i < CSRCAP) ebuf[i] = ed;
        atomicAdd(&lcnt[ed >> 17], 1);
    }
    __syncthreads();
    int v = 0, pdeg = 0;
    if (tid < 256) {
        v = lcnt[tid];
        pdeg = (v + 3) & ~3;
        stmp[tid] = pdeg;
    }
    __syncthreads();
    for (int off = 1; off < 256; off <<= 1) {
        int t = 0;
        if (tid < 256 && tid >= off) t = stmp[tid - off];
        __syncthreads();
        if (tid < 256 && tid >= off) stmp[tid] += t;
        __syncthreads();
    }
    if (tid < 256) {
        int ex = tid ? stmp[tid - 1] : 0;
        int slot = cbase + ex;
        lcur[tid] = slot;
        int node = nbase + tid;
        if (node < N_NODES) {
            rp[node] = make_int2(slot, slot + pdeg);
            deg_inv[node] = 1.0f / (float)(v > 1 ? v : 1);
            for (int s2 = slot + v; s2 < slot + pdeg; ++s2) col[s2] = N_NODES;  // pad
        }
    }
    __syncthreads();
    for (int i = tid; i < cnt; i += 512) {          // scatter from LDS
        int ed = (i < CSRCAP) ? ebuf[i] : bedge[ebeg + i];
        int pos = atomicAdd(&lcur[ed >> 17], 1);
        col[pos] = ed & 0x1FFFF;
    }
}

// ---------------- fused layer core: mean-agg (gather) -> LDS tile + phase-1 MFMA ------
// Wave owns 16 output nodes. Agg: 4-node groups, quad scheme, 16 gathers in flight
// (4-slot unroll), wave-uniform pad-slot redirect (col[0..7] -> zero row).

__device__ __forceinline__ void fused_core(const __half* __restrict__ Hin,
                                           const __half* __restrict__ Wf,
                                           const float* __restrict__ bias,
                                           const int2* __restrict__ rp,
                                           const int* __restrict__ col,
                                           const float* __restrict__ deg_inv, int n,
                                           __half (&lds)[16][72], int m0, int l,
                                           f32x4 (&acc)[4]) {
    int q = l >> 4, li = l & 15;
    int beg = 0, nq = 0;
    float dinv = 0.f;
    if (l < 16 && m0 + l < n) {
        int2 se = rp[m0 + l];
        beg = se.x;
        nq = (se.y - se.x) >> 2;
        dinv = deg_inv[m0 + l];
    }
    const uint2* x8 = (const uint2*)Hin;
    const int* cq = col + q;

#pragma unroll
    for (int g = 0; g < 4; ++g) {
        int b0 = __builtin_amdgcn_readlane(beg, 4 * g + 0);
        int b1 = __builtin_amdgcn_readlane(beg, 4 * g + 1);
        int b2 = __builtin_amdgcn_readlane(beg, 4 * g + 2);
        int b3 = __builtin_amdgcn_readlane(beg, 4 * g + 3);
        int c0 = __builtin_amdgcn_readlane(nq, 4 * g + 0);
        int c1 = __builtin_amdgcn_readlane(nq, 4 * g + 1);
        int c2 = __builtin_amdgcn_readlane(nq, 4 * g + 2);
        int c3 = __builtin_amdgcn_readlane(nq, 4 * g + 3);
        int qmax = max(max(c0, c1), max(c2, c3));
        __half2 s00 = __floats2half2_rn(0.f, 0.f), s01 = s00;
        __half2 s10 = s00, s11 = s00, s20 = s00, s21 = s00, s30 = s00, s31 = s00;
        for (int qq = 0; qq < qmax; qq += 4) {       // 16 gathers in flight
            int a[16];
#pragma unroll
            for (int s = 0; s < 4; ++s) {
                int o = (qq + s) * 4;
                a[s * 4 + 0] = qq + s < c0 ? b0 + o : 0;   // 0 -> reserved pad slots
                a[s * 4 + 1] = qq + s < c1 ? b1 + o : 0;
                a[s * 4 + 2] = qq + s < c2 ? b2 + o : 0;
                a[s * 4 + 3] = qq + s < c3 ? b3 + o : 0;
            }
            int idx[16];
#pragma unroll
            for (int i = 0; i < 16; ++i) idx[i] = cq[a[i]];
            uint2 u[16];
#pragma unroll
            for (int i = 0; i < 16; ++i) u[i] = x8[(size_t)idx[i] * 16 + li];
            union { unsigned v; __half2 h; } w;
#pragma unroll
            for (int s = 0; s < 4; ++s) {
                w.v = u[s * 4 + 0].x; s00 = __hadd2(s00, w.h);
                w.v = u[s * 4 + 0].y; s01 = __hadd2(s01, w.h);
                w.v = u[s * 4 + 1].x; s10 = __hadd2(s10, w.h);
                w.v = u[s * 4 + 1].y; s11 = __hadd2(s11, w.h);
                w.v = u[s * 4 + 2].x; s20 = __hadd2(s20, w.h);
                w.v = u[s * 4 + 2].y; s21 = __hadd2(s21, w.h);
                w.v = u[s * 4 + 3].x; s30 = __hadd2(s30, w.h);
                w.v = u[s * 4 + 3].y; s31 = __hadd2(s31, w.h);
            }
        }
        union { __half2 h; int i; } t;
#pragma unroll
        for (int m = 16; m < 64; m <<= 1) {
            t.h = s00; t.i = __shfl_xor(t.i, m); s00 = __hadd2(s00, t.h);
            t.h = s01; t.i = __shfl_xor(t.i, m); s01 = __hadd2(s01, t.h);
            t.h = s10; t.i = __shfl_xor(t.i, m); s10 = __hadd2(s10, t.h);
            t.h = s11; t.i = __shfl_xor(t.i, m); s11 = __hadd2(s11, t.h);
            t.h = s20; t.i = __shfl_xor(t.i, m); s20 = __hadd2(s20, t.h);
            t.h = s21; t.i = __shfl_xor(t.i, m); s21 = __hadd2(s21, t.h);
            t.h = s30; t.i = __shfl_xor(t.i, m); s30 = __hadd2(s30, t.h);
            t.h = s31; t.i = __shfl_xor(t.i, m); s31 = __hadd2(s31, t.h);
        }
        float d0 = rlf(dinv, 4 * g + 0);
        float d1 = rlf(dinv, 4 * g + 1);
        float d2 = rlf(dinv, 4 * g + 2);
        float d3 = rlf(dinv, 4 * g + 3);
        if (l < 16) {
            union { __half2 h; unsigned v; } p0, p1;
            float2 f;
            uint2 ov;
            f = __half22float2(s00); p0.h = __floats2half2_rn(f.x * d0, f.y * d0);
            f = __half22float2(s01); p1.h = __floats2half2_rn(f.x * d0, f.y * d0);
            ov.x = p0.v; ov.y = p1.v;
            *(uint2*)&lds[4 * g + 0][li * 4] = ov;
            f = __half22float2(s10); p0.h = __floats2half2_rn(f.x * d1, f.y * d1);
            f = __half22float2(s11); p1.h = __floats2half2_rn(f.x * d1, f.y * d1);
            ov.x = p0.v; ov.y = p1.v;
            *(uint2*)&lds[4 * g + 1][li * 4] = ov;
            f = __half22float2(s20); p0.h = __floats2half2_rn(f.x * d2, f.y * d2);
            f = __half22float2(s21); p1.h = __floats2half2_rn(f.x * d2, f.y * d2);
            ov.x = p0.v; ov.y = p1.v;
            *(uint2*)&lds[4 * g + 2][li * 4] = ov;
            f = __half22float2(s30); p0.h = __floats2half2_rn(f.x * d3, f.y * d3);
            f = __half22float2(s31); p1.h = __floats2half2_rn(f.x * d3, f.y * d3);
            ov.x = p0.v; ov.y = p1.v;
            *(uint2*)&lds[4 * g + 3][li * 4] = ov;
        }
    }

    // ---- phase-1 MFMA: [agg | self] @ W_cat + bias ----
    const f16x8* wf8 = (const f16x8*)Wf;
    f16x8 bf[4][4];
#pragma unroll
    for (int kt = 0; kt < 4; ++kt)
#pragma unroll
        for (int nt = 0; nt < 4; ++nt)
            bf[kt][nt] = wf8[(kt * 4 + nt) * 64 + l];
    int rowA = li;
#pragma unroll
    for (int nt = 0; nt < 4; ++nt) {
        float bs = bias[nt * 16 + rowA];
        acc[nt] = (f32x4){bs, bs, bs, bs};
    }
#pragma unroll
    for (int kt = 0; kt < 4; ++kt) {
        f16x8 a;
        if (kt < 2)
            a = *(const f16x8*)&lds[rowA][kt * 32 + q * 8];
        else
            a = *(const f16x8*)(Hin + (size_t)(m0 + rowA) * D + (kt - 2) * 32 + q * 8);
#pragma unroll
        for (int nt = 0; nt < 4; ++nt)
            acc[nt] = __builtin_amdgcn_mfma_f32_16x16x32_f16(a, bf[kt][nt], acc[nt], 0, 0, 0);
    }
}

// layers 1-2: relu -> fp16 Hout
__global__ __launch_bounds__(256) void k_fused(const __half* __restrict__ Hin,
                                               __half* __restrict__ Hout,
                                               const __half* __restrict__ Wf,
                                               const float* __restrict__ bias,
                                               const int2* __restrict__ rp,
                                               const int* __restrict__ col,
                                               const float* __restrict__ deg_inv, int n) {
    __shared__ __half lds[4][16][72];
    int l = threadIdx.x & 63;
    int wv = threadIdx.x >> 6;
    int m0 = blockIdx.x * 64 + wv * 16;
    f32x4 acc[4];
    fused_core(Hin, Wf, bias, rp, col, deg_inv, n, lds[wv], m0, l, acc);
    int q = l >> 4, rowA = l & 15;
#pragma unroll
    for (int nt = 0; nt < 4; ++nt)
#pragma unroll
        for (int qd = 0; qd < 4; ++qd) {
            int node = m0 + q * 4 + qd;
            float v = fmaxf(acc[nt][qd], 0.f);
            if (node < n)
                Hout[(size_t)node * D + nt * 16 + rowA] = __float2half(v);
        }
}

// layer 3 + fc fused: relu(h3) tile -> LDS -> MFMA with Wfc -> f32 out [N,32]
__global__ __launch_bounds__(256) void k_fused_fc(const __half* __restrict__ Hin,
                                                  float* __restrict__ out,
                                                  const __half* __restrict__ Wf,
                                                  const float* __restrict__ bias,
                                                  const __half* __restrict__ Wffc,
                                                  const float* __restrict__ bfc,
                                                  const int2* __restrict__ rp,
                                                  const int* __restrict__ col,
                                                  const float* __restrict__ deg_inv, int n) {
    __shared__ __half lds[4][16][72];
    int l = threadIdx.x & 63;
    int wv = threadIdx.x >> 6;
    int m0 = blockIdx.x * 64 + wv * 16;
    f32x4 acc[4];
    fused_core(Hin, Wf, bias, rp, col, deg_inv, n, lds[wv], m0, l, acc);
    int q = l >> 4, li = l & 15;

    // store relu(h3) tile back into the wave-private LDS tile (phase-1 reads done)
#pragma unroll
    for (int nt = 0; nt < 4; ++nt)
#pragma unroll
        for (int qd = 0; qd < 4; ++qd)
            lds[wv][q * 4 + qd][nt * 16 + li] = __float2half(fmaxf(acc[nt][qd], 0.f));

    // phase-2 MFMA: h3 @ Wfc^T + bfc   (K=64, NOUT=32)
    const f16x8* wfc8 = (const f16x8*)Wffc;
    f16x8 bf2[2][2];
#pragma unroll
    for (int kt = 0; kt < 2; ++kt)
#pragma unroll
        for (int nt = 0; nt < 2; ++nt)
            bf2[kt][nt] = wfc8[(kt * 2 + nt) * 64 + l];
    f32x4 acc2[2];
#pragma unroll
    for (int nt = 0; nt < 2; ++nt) {
        float bs = bfc[nt * 16 + li];
        acc2[nt] = (f32x4){bs, bs, bs, bs};
    }
#pragma unroll
    for (int kt = 0; kt < 2; ++kt) {
        f16x8 a = *(const f16x8*)&lds[wv][li][kt * 32 + q * 8];
#pragma unroll
        for (int nt = 0; nt < 2; ++nt)
            acc2[nt] = __builtin_amdgcn_mfma_f32_16x16x32_f16(a, bf2[kt][nt], acc2[nt], 0, 0, 0);
    }
#pragma unroll
    for (int nt = 0; nt < 2; ++nt)
#pragma unroll
        for (int qd = 0; qd < 4; ++qd) {
            int node = m0 + q * 4 + qd;
            if (node < n)
                out[(size_t)node * 32 + nt * 16 + li] = acc2[nt][qd];
        }
}

// ---------------- launch ----------------

extern "C" void kernel_launch(void* const* d_in, const int* in_sizes, int n_in,
                              void* d_out, int out_size, void* d_ws, size_t ws_size,
                              hipStream_t stream) {
    const float* x   = (const float*)d_in[0];
    const int*   ei  = (const int*)d_in[1];
    const int    E   = in_sizes[1] / 2;
    const int*   src = ei;
    const int*   dst = ei + E;
    const float* W1l = (const float*)d_in[2];
    const float* b1l = (const float*)d_in[3];
    const float* W1r = (const float*)d_in[4];
    const float* W2l = (const float*)d_in[5];
    const float* b2l = (const float*)d_in[6];
    const float* W2r = (const float*)d_in[7];
    const float* W3l = (const float*)d_in[8];
    const float* b3l = (const float*)d_in[9];
    const float* W3r = (const float*)d_in[10];
    const float* Wfc = (const float*)d_in[11];
    const float* bfc = (const float*)d_in[12];
    float* out = (float*)d_out;

    const int ga      = (E + ECH - 1) / ECH;
    const int entries = NB * ga;
    const int padded  = (entries + 1023) & ~1023;
    const int ntail   = padded - entries;
    const int nb2     = padded / 1024;

    char* p = (char*)d_ws;
    size_t off = 0;
    auto take = [&](size_t bytes) -> void* {
        void* r = p + off;
        off = (off + bytes + 255) & ~(size_t)255;
        return r;
    };
    __half* x16    = (__half*)take((size_t)NROWPAD * D * 2);
    __half* H1     = (__half*)take((size_t)NROWPAD * D * 2);
    __half* H2     = (__half*)take((size_t)NROWPAD * D * 2);
    float* deg_inv = (float*)take((size_t)N_NODES * 4);
    int2*  rp      = (int2*)take((size_t)N_NODES * 8);
    int*   histT   = (int*)take((size_t)padded * 4);
    int*   offs    = (int*)take((size_t)padded * 4);
    int*   bsums   = (int*)take(256 * 4);
    int*   bedge   = (int*)take((size_t)E * 4);
    int*   col     = (int*)take((size_t)(E + NB * BR * 4 + 72) * 4);
    __half* Wf1    = (__half*)take(8192 * 2);
    __half* Wf2    = (__half*)take(8192 * 2);
    __half* Wf3    = (__half*)take(8192 * 2);
    __half* Wffc   = (__half*)take(2048 * 2);

    int n4 = N_NODES * D / 4;
    int gp = (65536 + n4 + 255) / 256;
    k_prep<<<gp, 256, 0, stream>>>(W1l, W1r, W2l, W2r, W3l, W3r, Wfc,
                                   Wf1, Wf2, Wf3, Wffc,
                                   (unsigned*)x16, (unsigned*)H1, (unsigned*)H2,
                                   histT, entries, ntail, (const float4*)x, n4);

    k_hist<<<ga, 512, 0, stream>>>(dst, histT, E, ga);
    k_scan1<<<nb2, 256, 0, stream>>>(histT, offs, bsums);
    k_scan2<<<1, 256, 0, stream>>>(bsums, nb2, col);
    k_part<<<ga, 512, 0, stream>>>(src, dst, offs, bsums, bedge, E, ga);
    k_csr<<<NB, 512, 0, stream>>>(bedge, offs, bsums, col, rp, deg_inv, E, ga);

    int gg = NROWPAD / 64;             // 64 nodes per block

    // fused layers: agg + linear + relu; layer 3 also applies the final fc
    k_fused<<<gg, 256, 0, stream>>>(x16, H1, Wf1, b1l, rp, col, deg_inv, N_NODES);
    k_fused<<<gg, 256, 0, stream>>>(H1, H2, Wf2, b2l, rp, col, deg_inv, N_NODES);
    k_fused_fc<<<gg, 256, 0, stream>>>(H2, out, Wf3, b3l, Wffc, bfc, rp, col, deg_inv, N_NODES);
}

// Round 11
// 171.715 us; speedup vs baseline: 1.0648x; 1.0648x over previous
//
#include <hip/hip_runtime.h>
#include <hip/hip_fp16.h>

#define N_NODES 100000
#define D 64
#define BR 256                     // nodes per bucket
#define NB 391                     // ceil(N_NODES / BR)
#define ECH 2560                   // edges per hist/partition block
#define NROWPAD 100096             // row capacity for feature buffers (>=N_NODES+1)
#define CSRCAP 6144                // LDS edge-staging capacity per bucket (+30 sigma)

typedef _Float16 f16x8 __attribute__((ext_vector_type(8)));
typedef float f32x4 __attribute__((ext_vector_type(4)));

__device__ __forceinline__ float rlf(float v, int l) {
    union { float f; int i; } u;
    u.f = v;
    u.i = __builtin_amdgcn_readlane(u.i, l);
    return u.f;
}

// ---------------- weight prep + x->fp16 + dummy-row zero + histT tail zero ------------
// frag f=(kt*NT+nt): elem (lane,i) = W_cat[kt*32+(lane>>4)*8+i][nt*16+(lane&15)]
__global__ __launch_bounds__(256) void k_prep(const float* __restrict__ Wl1, const float* __restrict__ Wr1,
                                              const float* __restrict__ Wl2, const float* __restrict__ Wr2,
                                              const float* __restrict__ Wl3, const float* __restrict__ Wr3,
                                              const float* __restrict__ Wfc,
                                              __half* __restrict__ Wf1, __half* __restrict__ Wf2,
                                              __half* __restrict__ Wf3, __half* __restrict__ Wffc,
                                              unsigned* __restrict__ x16, unsigned* __restrict__ H1,
                                              unsigned* __restrict__ H2,
                                              int* __restrict__ histT, int entries, int ntail,
                                              const float4* __restrict__ x, int n4) {
    int t = blockIdx.x * 256 + threadIdx.x;
    if (t >= 65536) {                      // x -> fp16 (bulk of the grid)
        int i = t - 65536;
        if (i < n4) {
            float4 v = x[i];
            union { __half2 h[2]; uint2 u; } pk;
            pk.h[0] = __floats2half2_rn(v.x, v.y);
            pk.h[1] = __floats2half2_rn(v.z, v.w);
            ((uint2*)x16)[i] = pk.u;
        }
    } else if (t < 24576) {                // 3 layers x 16 frags x 512
        int layer = t / 8192;
        int r = t % 8192;
        int f = r >> 9, rem = r & 511;
        int lane = rem >> 3, i = rem & 7;
        int kt = f >> 2, nt = f & 3;
        int k = kt * 32 + (lane >> 4) * 8 + i;   // 0..127 over [Wl|Wr]
        int o = nt * 16 + (lane & 15);
        const float* Wl = layer == 0 ? Wl1 : layer == 1 ? Wl2 : Wl3;
        const float* Wr = layer == 0 ? Wr1 : layer == 1 ? Wr2 : Wr3;
        float v = (k < 64) ? Wl[o * 64 + k] : Wr[o * 64 + (k - 64)];
        __half* Wf = layer == 0 ? Wf1 : layer == 1 ? Wf2 : Wf3;
        Wf[r] = __float2half(v);
    } else if (t < 26624) {                // fc: 4 frags x 512
        int r = t - 24576;
        int f = r >> 9, rem = r & 511;
        int lane = rem >> 3, i = rem & 7;
        int kt = f >> 1, nt = f & 1;
        int k = kt * 32 + (lane >> 4) * 8 + i;
        int o = nt * 16 + (lane & 15);
        Wffc[r] = __float2half(Wfc[o * 64 + k]);
    } else if (t < 26720) {                // zero dummy row N_NODES (32 uints each)
        int z = t - 26624;                 // 0..95
        unsigned* buf = (z >> 5) == 0 ? x16 : (z >> 5) == 1 ? H1 : H2;
        buf[(size_t)N_NODES * 32 + (z & 31)] = 0u;
    } else if (t >= 32768 && t < 32768 + ntail) {
        histT[entries + (t - 32768)] = 0;  // zero only the scan-padding tail
    }
}

// ---------------- CSR build (no global atomics) ----------------

__global__ __launch_bounds__(512) void k_hist(const int* __restrict__ dst,
                                              int* __restrict__ histT,
                                              int E, int ga) {
    __shared__ int h[NB];
    int blk = blockIdx.x, tid = threadIdx.x;
    for (int i = tid; i < NB; i += 512) h[i] = 0;
    __syncthreads();
    int base = blk * ECH;
    int lim = E - base; if (lim > ECH) lim = ECH;
    for (int i = tid; i < lim; i += 512)
        atomicAdd(&h[dst[base + i] >> 8], 1);
    __syncthreads();
    for (int i = tid; i < NB; i += 512)
        histT[i * ga + blk] = h[i];
}

__global__ __launch_bounds__(256) void k_scan1(const int* __restrict__ cnt,
                                               int* __restrict__ part,
                                               int* __restrict__ bsums) {
    __shared__ int s[256];
    int tid = threadIdx.x;
    int i4 = blockIdx.x * 256 + tid;
    int4 v = reinterpret_cast<const int4*>(cnt)[i4];
    int tsum = v.x + v.y + v.z + v.w;
    s[tid] = tsum;
    __syncthreads();
    for (int off = 1; off < 256; off <<= 1) {
        int t = 0;
        if (tid >= off) t = s[tid - off];
        __syncthreads();
        if (tid >= off) s[tid] += t;
        __syncthreads();
    }
    int excl = tid ? s[tid - 1] : 0;
    if (tid == 255) bsums[blockIdx.x] = s[255];
    int4 o;
    o.x = excl;
    o.y = o.x + v.x;
    o.z = o.y + v.y;
    o.w = o.z + v.z;
    reinterpret_cast<int4*>(part)[i4] = o;
}

// scan of block sums; also initializes the reserved col pad slots [0..7] = N_NODES
__global__ __launch_bounds__(256) void k_scan2(int* __restrict__ bsums, int nb,
                                               int* __restrict__ col) {
    __shared__ int s[256];
    int tid = threadIdx.x;
    if (tid < 8) col[tid] = N_NODES;
    int v = (tid < nb) ? bsums[tid] : 0;
    s[tid] = v;
    __syncthreads();
    for (int off = 1; off < 256; off <<= 1) {
        int t = 0;
        if (tid >= off) t = s[tid - off];
        __syncthreads();
        if (tid >= off) s[tid] += t;
        __syncthreads();
    }
    if (tid < nb) bsums[tid] = tid ? s[tid - 1] : 0;
}

// partition into bucket-major, packed edge = src | (ldst<<17); bsums folded in
__global__ __launch_bounds__(512) void k_part(const int* __restrict__ src,
                                              const int* __restrict__ dst,
                                              const int* __restrict__ offs,
                                              const int* __restrict__ bsums,
                                              int* __restrict__ bedge,
                                              int E, int ga) {
    __shared__ int o[NB];
    int blk = blockIdx.x, tid = threadIdx.x;
    for (int i = tid; i < NB; i += 512) {
        int ent = i * ga + blk;
        o[i] = offs[ent] + bsums[ent >> 10];
    }
    __syncthreads();
    int base = blk * ECH;
    int lim = E - base; if (lim > ECH) lim = ECH;
    for (int i = tid; i < lim; i += 512) {
        int e = base + i;
        int d = dst[e];
        int pos = atomicAdd(&o[d >> 8], 1);
        bedge[pos] = src[e] | ((d & 255) << 17);
    }
}

// per-bucket CSR, single global pass: edges staged in LDS during counting, scattered
// from LDS. Degree padded to x4; dummy index = N_NODES (zero row). col region for
// bucket b: [ebeg + b*1024 + 8, ...) — slots 0..7 reserved as pad target.
__global__ __launch_bounds__(512) void k_csr(const int* __restrict__ bedge,
                                             const int* __restrict__ offs,
                                             const int* __restrict__ bsums,
                                             int* __restrict__ col,
                                             int2* __restrict__ rp,
                                             float* __restrict__ deg_inv,
                                             int E, int ga) {
    __shared__ int ebuf[CSRCAP];
    __shared__ int lcnt[BR];
    __shared__ int stmp[BR];
    __shared__ int lcur[BR];
    int b = blockIdx.x, tid = threadIdx.x;
    int e0 = b * ga;
    int ebeg = offs[e0] + bsums[e0 >> 10];
    int eend = E;
    if (b + 1 < NB) {
        int e1 = (b + 1) * ga;
        eend = offs[e1] + bsums[e1 >> 10];
    }
    int cnt = eend - ebeg;
    int nbase = b * BR;
    int cbase = ebeg + b * (BR * 4) + 8;
    if (tid < 256) lcnt[tid] = 0;
    __syncthreads();
    for (int i = tid; i < cnt; i += 512) {          // single global read pass
        int ed = bedge[ebeg + i];
        if (i < CSRCAP) ebuf[i] = ed;
        atomicAdd(&lcnt[ed >> 17], 1);
    }
    __syncthreads();
    int v = 0, pdeg = 0;
    if (tid < 256) {
        v = lcnt[tid];
        pdeg = (v + 3) & ~3;
        stmp[tid] = pdeg;
    }
    __syncthreads();
    for (int off = 1; off < 256; off <<= 1) {
        int t = 0;
        if (tid < 256 && tid >= off) t = stmp[tid - off];
        __syncthreads();
        if (tid < 256 && tid >= off) stmp[tid] += t;
        __syncthreads();
    }
    if (tid < 256) {
        int ex = tid ? stmp[tid - 1] : 0;
        int slot = cbase + ex;
        lcur[tid] = slot;
        int node = nbase + tid;
        if (node < N_NODES) {
            rp[node] = make_int2(slot, slot + pdeg);
            deg_inv[node] = 1.0f / (float)(v > 1 ? v : 1);
            for (int s2 = slot + v; s2 < slot + pdeg; ++s2) col[s2] = N_NODES;  // pad
        }
    }
    __syncthreads();
    for (int i = tid; i < cnt; i += 512) {          // scatter from LDS
        int ed = (i < CSRCAP) ? ebuf[i] : bedge[ebeg + i];
        int pos = atomicAdd(&lcur[ed >> 17], 1);
        col[pos] = ed & 0x1FFFF;
    }
}

// ---------------- fused layer core: mean-agg (gather) -> LDS tile + phase-1 MFMA ------
// Wave owns 16 output nodes. Agg: 4-node groups, quad scheme (q=edge-in-quad,
// li=half4 col), 8 gathers in flight, wave-uniform pad-slot redirect (col[0..7] ->
// zero row). Self-row prefetched into regs before the gather phase.

__device__ __forceinline__ void fused_core(const __half* __restrict__ Hin,
                                           const __half* __restrict__ Wf,
                                           const float* __restrict__ bias,
                                           const int2* __restrict__ rp,
                                           const int* __restrict__ col,
                                           const float* __restrict__ deg_inv, int n,
                                           __half (&lds)[16][72], int m0, int l,
                                           f32x4 (&acc)[4]) {
    int q = l >> 4, li = l & 15;
    int beg = 0, nq = 0;
    float dinv = 0.f;
    if (l < 16 && m0 + l < n) {
        int2 se = rp[m0 + l];
        beg = se.x;
        nq = (se.y - se.x) >> 2;
        dinv = deg_inv[m0 + l];
    }
    // prefetch self-row halves (used by phase-1 MFMA kt=2,3) — retires under gather
    const __half* selfp = Hin + (size_t)(m0 + li) * D;
    f16x8 self0 = *(const f16x8*)(selfp + q * 8);
    f16x8 self1 = *(const f16x8*)(selfp + 32 + q * 8);

    const uint2* x8 = (const uint2*)Hin;
    const int* cq = col + q;

#pragma unroll
    for (int g = 0; g < 4; ++g) {
        int b0 = __builtin_amdgcn_readlane(beg, 4 * g + 0);
        int b1 = __builtin_amdgcn_readlane(beg, 4 * g + 1);
        int b2 = __builtin_amdgcn_readlane(beg, 4 * g + 2);
        int b3 = __builtin_amdgcn_readlane(beg, 4 * g + 3);
        int c0 = __builtin_amdgcn_readlane(nq, 4 * g + 0);
        int c1 = __builtin_amdgcn_readlane(nq, 4 * g + 1);
        int c2 = __builtin_amdgcn_readlane(nq, 4 * g + 2);
        int c3 = __builtin_amdgcn_readlane(nq, 4 * g + 3);
        int qmax = max(max(c0, c1), max(c2, c3));
        __half2 s00 = __floats2half2_rn(0.f, 0.f), s01 = s00;
        __half2 s10 = s00, s11 = s00, s20 = s00, s21 = s00, s30 = s00, s31 = s00;
        for (int qq = 0; qq < qmax; qq += 2) {
            int o = qq * 4;
            int a0 = qq < c0 ? b0 + o : 0;           // 0 -> reserved pad slots
            int a1 = qq < c1 ? b1 + o : 0;
            int a2 = qq < c2 ? b2 + o : 0;
            int a3 = qq < c3 ? b3 + o : 0;
            int a4 = qq + 1 < c0 ? b0 + o + 4 : 0;
            int a5 = qq + 1 < c1 ? b1 + o + 4 : 0;
            int a6 = qq + 1 < c2 ? b2 + o + 4 : 0;
            int a7 = qq + 1 < c3 ? b3 + o + 4 : 0;
            int i0 = cq[a0], i1 = cq[a1], i2 = cq[a2], i3 = cq[a3];
            int i4 = cq[a4], i5 = cq[a5], i6 = cq[a6], i7 = cq[a7];
            uint2 u0 = x8[(size_t)i0 * 16 + li];
            uint2 u1 = x8[(size_t)i1 * 16 + li];
            uint2 u2 = x8[(size_t)i2 * 16 + li];
            uint2 u3 = x8[(size_t)i3 * 16 + li];
            uint2 u4 = x8[(size_t)i4 * 16 + li];
            uint2 u5 = x8[(size_t)i5 * 16 + li];
            uint2 u6 = x8[(size_t)i6 * 16 + li];
            uint2 u7 = x8[(size_t)i7 * 16 + li];
            union { unsigned v; __half2 h; } w;
            w.v = u0.x; s00 = __hadd2(s00, w.h);
            w.v = u0.y; s01 = __hadd2(s01, w.h);
            w.v = u1.x; s10 = __hadd2(s10, w.h);
            w.v = u1.y; s11 = __hadd2(s11, w.h);
            w.v = u2.x; s20 = __hadd2(s20, w.h);
            w.v = u2.y; s21 = __hadd2(s21, w.h);
            w.v = u3.x; s30 = __hadd2(s30, w.h);
            w.v = u3.y; s31 = __hadd2(s31, w.h);
            w.v = u4.x; s00 = __hadd2(s00, w.h);
            w.v = u4.y; s01 = __hadd2(s01, w.h);
            w.v = u5.x; s10 = __hadd2(s10, w.h);
            w.v = u5.y; s11 = __hadd2(s11, w.h);
            w.v = u6.x; s20 = __hadd2(s20, w.h);
            w.v = u6.y; s21 = __hadd2(s21, w.h);
            w.v = u7.x; s30 = __hadd2(s30, w.h);
            w.v = u7.y; s31 = __hadd2(s31, w.h);
        }
        union { __half2 h; int i; } t;
#pragma unroll
        for (int m = 16; m < 64; m <<= 1) {
            t.h = s00; t.i = __shfl_xor(t.i, m); s00 = __hadd2(s00, t.h);
            t.h = s01; t.i = __shfl_xor(t.i, m); s01 = __hadd2(s01, t.h);
            t.h = s10; t.i = __shfl_xor(t.i, m); s10 = __hadd2(s10, t.h);
            t.h = s11; t.i = __shfl_xor(t.i, m); s11 = __hadd2(s11, t.h);
            t.h = s20; t.i = __shfl_xor(t.i, m); s20 = __hadd2(s20, t.h);
            t.h = s21; t.i = __shfl_xor(t.i, m); s21 = __hadd2(s21, t.h);
            t.h = s30; t.i = __shfl_xor(t.i, m); s30 = __hadd2(s30, t.h);
            t.h = s31; t.i = __shfl_xor(t.i, m); s31 = __hadd2(s31, t.h);
        }
        float d0 = rlf(dinv, 4 * g + 0);
        float d1 = rlf(dinv, 4 * g + 1);
        float d2 = rlf(dinv, 4 * g + 2);
        float d3 = rlf(dinv, 4 * g + 3);
        if (l < 16) {
            union { __half2 h; unsigned v; } p0, p1;
            float2 f;
            uint2 ov;
            f = __half22float2(s00); p0.h = __floats2half2_rn(f.x * d0, f.y * d0);
            f = __half22float2(s01); p1.h = __floats2half2_rn(f.x * d0, f.y * d0);
            ov.x = p0.v; ov.y = p1.v;
            *(uint2*)&lds[4 * g + 0][li * 4] = ov;
            f = __half22float2(s10); p0.h = __floats2half2_rn(f.x * d1, f.y * d1);
            f = __half22float2(s11); p1.h = __floats2half2_rn(f.x * d1, f.y * d1);
            ov.x = p0.v; ov.y = p1.v;
            *(uint2*)&lds[4 * g + 1][li * 4] = ov;
            f = __half22float2(s20); p0.h = __floats2half2_rn(f.x * d2, f.y * d2);
            f = __half22float2(s21); p1.h = __floats2half2_rn(f.x * d2, f.y * d2);
            ov.x = p0.v; ov.y = p1.v;
            *(uint2*)&lds[4 * g + 2][li * 4] = ov;
            f = __half22float2(s30); p0.h = __floats2half2_rn(f.x * d3, f.y * d3);
            f = __half22float2(s31); p1.h = __floats2half2_rn(f.x * d3, f.y * d3);
            ov.x = p0.v; ov.y = p1.v;
            *(uint2*)&lds[4 * g + 3][li * 4] = ov;
        }
    }

    // ---- phase-1 MFMA: [agg | self] @ W_cat + bias ----
    const f16x8* wf8 = (const f16x8*)Wf;
    f16x8 bf[4][4];
#pragma unroll
    for (int kt = 0; kt < 4; ++kt)
#pragma unroll
        for (int nt = 0; nt < 4; ++nt)
            bf[kt][nt] = wf8[(kt * 4 + nt) * 64 + l];
    int rowA = li;
#pragma unroll
    for (int nt = 0; nt < 4; ++nt) {
        float bs = bias[nt * 16 + rowA];
        acc[nt] = (f32x4){bs, bs, bs, bs};
    }
#pragma unroll
    for (int kt = 0; kt < 4; ++kt) {
        f16x8 a;
        if (kt < 2)
            a = *(const f16x8*)&lds[rowA][kt * 32 + q * 8];
        else
            a = (kt == 2) ? self0 : self1;
#pragma unroll
        for (int nt = 0; nt < 4; ++nt)
            acc[nt] = __builtin_amdgcn_mfma_f32_16x16x32_f16(a, bf[kt][nt], acc[nt], 0, 0, 0);
    }
}

// layers 1-2: relu -> fp16 Hout
__global__ __launch_bounds__(256) void k_fused(const __half* __restrict__ Hin,
                                               __half* __restrict__ Hout,
                                               const __half* __restrict__ Wf,
                                               const float* __restrict__ bias,
                                               const int2* __restrict__ rp,
                                               const int* __restrict__ col,
                                               const float* __restrict__ deg_inv, int n) {
    __shared__ __half lds[4][16][72];
    int l = threadIdx.x & 63;
    int wv = threadIdx.x >> 6;
    int m0 = blockIdx.x * 64 + wv * 16;
    f32x4 acc[4];
    fused_core(Hin, Wf, bias, rp, col, deg_inv, n, lds[wv], m0, l, acc);
    int q = l >> 4, rowA = l & 15;
#pragma unroll
    for (int nt = 0; nt < 4; ++nt)
#pragma unroll
        for (int qd = 0; qd < 4; ++qd) {
            int node = m0 + q * 4 + qd;
            float v = fmaxf(acc[nt][qd], 0.f);
            if (node < n)
                Hout[(size_t)node * D + nt * 16 + rowA] = __float2half(v);
        }
}

// layer 3 + fc fused: relu(h3) tile -> LDS -> MFMA with Wfc -> f32 out [N,32]
__global__ __launch_bounds__(256) void k_fused_fc(const __half* __restrict__ Hin,
                                                  float* __restrict__ out,
                                                  const __half* __restrict__ Wf,
                                                  const float* __restrict__ bias,
                                                  const __half* __restrict__ Wffc,
                                                  const float* __restrict__ bfc,
                                                  const int2* __restrict__ rp,
                                                  const int* __restrict__ col,
                                                  const float* __restrict__ deg_inv, int n) {
    __shared__ __half lds[4][16][72];
    int l = threadIdx.x & 63;
    int wv = threadIdx.x >> 6;
    int m0 = blockIdx.x * 64 + wv * 16;
    f32x4 acc[4];
    fused_core(Hin, Wf, bias, rp, col, deg_inv, n, lds[wv], m0, l, acc);
    int q = l >> 4, li = l & 15;

    // store relu(h3) tile back into the wave-private LDS tile (phase-1 reads done)
#pragma unroll
    for (int nt = 0; nt < 4; ++nt)
#pragma unroll
        for (int qd = 0; qd < 4; ++qd)
            lds[wv][q * 4 + qd][nt * 16 + li] = __float2half(fmaxf(acc[nt][qd], 0.f));

    // phase-2 MFMA: h3 @ Wfc^T + bfc   (K=64, NOUT=32)
    const f16x8* wfc8 = (const f16x8*)Wffc;
    f16x8 bf2[2][2];
#pragma unroll
    for (int kt = 0; kt < 2; ++kt)
#pragma unroll
        for (int nt = 0; nt < 2; ++nt)
            bf2[kt][nt] = wfc8[(kt * 2 + nt) * 64 + l];
    f32x4 acc2[2];
#pragma unroll
    for (int nt = 0; nt < 2; ++nt) {
        float bs = bfc[nt * 16 + li];
        acc2[nt] = (f32x4){bs, bs, bs, bs};
    }
#pragma unroll
    for (int kt = 0; kt < 2; ++kt) {
        f16x8 a = *(const f16x8*)&lds[wv][li][kt * 32 + q * 8];
#pragma unroll
        for (int nt = 0; nt < 2; ++nt)
            acc2[nt] = __builtin_amdgcn_mfma_f32_16x16x32_f16(a, bf2[kt][nt], acc2[nt], 0, 0, 0);
    }
#pragma unroll
    for (int nt = 0; nt < 2; ++nt)
#pragma unroll
        for (int qd = 0; qd < 4; ++qd) {
            int node = m0 + q * 4 + qd;
            if (node < n)
                out[(size_t)node * 32 + nt * 16 + li] = acc2[nt][qd];
        }
}

// ---------------- launch ----------------

extern "C" void kernel_launch(void* const* d_in, const int* in_sizes, int n_in,
                              void* d_out, int out_size, void* d_ws, size_t ws_size,
                              hipStream_t stream) {
    const float* x   = (const float*)d_in[0];
    const int*   ei  = (const int*)d_in[1];
    const int    E   = in_sizes[1] / 2;
    const int*   src = ei;
    const int*   dst = ei + E;
    const float* W1l = (const float*)d_in[2];
    const float* b1l = (const float*)d_in[3];
    const float* W1r = (const float*)d_in[4];
    const float* W2l = (const float*)d_in[5];
    const float* b2l = (const float*)d_in[6];
    const float* W2r = (const float*)d_in[7];
    const float* W3l = (const float*)d_in[8];
    const float* b3l = (const float*)d_in[9];
    const float* W3r = (const float*)d_in[10];
    const float* Wfc = (const float*)d_in[11];
    const float* bfc = (const float*)d_in[12];
    float* out = (float*)d_out;

    const int ga      = (E + ECH - 1) / ECH;
    const int entries = NB * ga;
    const int padded  = (entries + 1023) & ~1023;
    const int ntail   = padded - entries;
    const int nb2     = padded / 1024;

    char* p = (char*)d_ws;
    size_t off = 0;
    auto take = [&](size_t bytes) -> void* {
        void* r = p + off;
        off = (off + bytes + 255) & ~(size_t)255;
        return r;
    };
    __half* x16    = (__half*)take((size_t)NROWPAD * D * 2);
    __half* H1     = (__half*)take((size_t)NROWPAD * D * 2);
    __half* H2     = (__half*)take((size_t)NROWPAD * D * 2);
    float* deg_inv = (float*)take((size_t)N_NODES * 4);
    int2*  rp      = (int2*)take((size_t)N_NODES * 8);
    int*   histT   = (int*)take((size_t)padded * 4);
    int*   offs    = (int*)take((size_t)padded * 4);
    int*   bsums   = (int*)take(256 * 4);
    int*   bedge   = (int*)take((size_t)E * 4);
    int*   col     = (int*)take((size_t)(E + NB * BR * 4 + 72) * 4);
    __half* Wf1    = (__half*)take(8192 * 2);
    __half* Wf2    = (__half*)take(8192 * 2);
    __half* Wf3    = (__half*)take(8192 * 2);
    __half* Wffc   = (__half*)take(2048 * 2);

    int n4 = N_NODES * D / 4;
    int gp = (65536 + n4 + 255) / 256;
    k_prep<<<gp, 256, 0, stream>>>(W1l, W1r, W2l, W2r, W3l, W3r, Wfc,
                                   Wf1, Wf2, Wf3, Wffc,
                                   (unsigned*)x16, (unsigned*)H1, (unsigned*)H2,
                                   histT, entries, ntail, (const float4*)x, n4);

    k_hist<<<ga, 512, 0, stream>>>(dst, histT, E, ga);
    k_scan1<<<nb2, 256, 0, stream>>>(histT, offs, bsums);
    k_scan2<<<1, 256, 0, stream>>>(bsums, nb2, col);
    k_part<<<ga, 512, 0, stream>>>(src, dst, offs, bsums, bedge, E, ga);
    k_csr<<<NB, 512, 0, stream>>>(bedge, offs, bsums, col, rp, deg_inv, E, ga);

    int gg = NROWPAD / 64;             // 64 nodes per block

    // fused layers: agg + linear + relu; layer 3 also applies the final fc
    k_fused<<<gg, 256, 0, stream>>>(x16, H1, Wf1, b1l, rp, col, deg_inv, N_NODES);
    k_fused<<<gg, 256, 0, stream>>>(H1, H2, Wf2, b2l, rp, col, deg_inv, N_NODES);
    k_fused_fc<<<gg, 256, 0, stream>>>(H2, out, Wf3, b3l, Wffc, bfc, rp, col, deg_inv, N_NODES);
}